// Round 1
// baseline (21399.858 us; speedup 1.0000x reference)
//
#include <hip/hip_runtime.h>
#include <hip/hip_bf16.h>

#define L 12
#define D 1024
#define H 16
#define DH 64
#define S 512
#define B 4
#define V 16386
#define NT 16
#define M_ROWS (B * S)   // 2048

// ---------------------------------------------------------------- embedding
__global__ __launch_bounds__(256) void embed_kernel(
    const int* __restrict__ ids, const int* __restrict__ tts,
    const float* __restrict__ wte, const float* __restrict__ wtte,
    const float* __restrict__ wpe, float* __restrict__ h)
{
    int row = blockIdx.x;            // b*S + s
    int s = row % S;
    int id = ids[row], tt = tts[row];
    int c = threadIdx.x * 4;         // 256 threads * 4 = 1024 = D
    const float4 a = *(const float4*)(wte  + (size_t)id * D + c);
    const float4 p = *(const float4*)(wpe  + (size_t)s  * D + c);
    const float4 t = *(const float4*)(wtte + (size_t)tt * D + c);
    float4 r;
    r.x = a.x + p.x + t.x; r.y = a.y + p.y + t.y;
    r.z = a.z + p.z + t.z; r.w = a.w + p.w + t.w;
    *(float4*)(h + (size_t)row * D + c) = r;
}

// ---------------------------------------------------------------- layernorm
__global__ __launch_bounds__(256) void ln_kernel(
    const float* __restrict__ x, const float* __restrict__ w,
    const float* __restrict__ b, float* __restrict__ y)
{
    int row = blockIdx.x;
    int c = threadIdx.x * 4;
    const float* xr = x + (size_t)row * D;
    float4 v = *(const float4*)(xr + c);
    float s  = v.x + v.y + v.z + v.w;
    float ss = v.x*v.x + v.y*v.y + v.z*v.z + v.w*v.w;
    for (int off = 32; off; off >>= 1) {
        s  += __shfl_xor(s, off);
        ss += __shfl_xor(ss, off);
    }
    __shared__ float sm[8];
    int lane = threadIdx.x & 63, wv = threadIdx.x >> 6;
    if (lane == 0) { sm[wv] = s; sm[4 + wv] = ss; }
    __syncthreads();
    s  = sm[0] + sm[1] + sm[2] + sm[3];
    ss = sm[4] + sm[5] + sm[6] + sm[7];
    float mu  = s * (1.0f / D);
    float var = ss * (1.0f / D) - mu * mu;
    float rstd = rsqrtf(var + 1e-5f);
    float4 wv4 = *(const float4*)(w + c);
    float4 bv4 = *(const float4*)(b + c);
    float4 o;
    o.x = (v.x - mu) * rstd * wv4.x + bv4.x;
    o.y = (v.y - mu) * rstd * wv4.y + bv4.y;
    o.z = (v.z - mu) * rstd * wv4.z + bv4.z;
    o.w = (v.w - mu) * rstd * wv4.w + bv4.w;
    *(float4*)(y + (size_t)row * D + c) = o;
}

// ---------------------------------------------------------------- GEMM
// C[M,N] = act(A[M,K] @ Bm[K,N] + bias[N]) (+ res[M,N])
// BM=BN=64, BK=16, 256 threads, 4x4 microtile per thread.
// M must be a multiple of 64 and K a multiple of 16; N is guarded.
#define BM 64
#define BN 64
#define BK 16

__device__ inline float gelu_new(float x)
{
    float a = 0.7978845608028654f * (x + 0.044715f * x * x * x);
    float e = __expf(-2.0f * fabsf(a));          // tanh via exp, overflow-safe
    float t = (1.0f - e) / (1.0f + e);
    t = (a >= 0.0f) ? t : -t;
    return 0.5f * x * (1.0f + t);
}

__global__ __launch_bounds__(256) void gemm_kernel(
    const float* __restrict__ A, const float* __restrict__ Bm,
    const float* __restrict__ bias, const float* __restrict__ res,
    float* __restrict__ C, int M, int N, int K, int dogelu)
{
    __shared__ float As[BK][BM + 4];
    __shared__ float Bs[BK][BN + 4];
    int tid = threadIdx.x;
    int bm = blockIdx.y * BM;
    int bn = blockIdx.x * BN;
    int tr = tid / 16;          // 0..15 (row group)
    int tc = tid % 16;          // 0..15 (col group)
    int arow  = tid / 4;        // 0..63
    int acol4 = (tid % 4) * 4;  // 0,4,8,12
    int brow  = tid / 16;       // 0..15
    int bcol  = (tid % 16) * 4; // 0..60

    float acc[4][4] = {};

    for (int k0 = 0; k0 < K; k0 += BK) {
        float4 a4 = *(const float4*)(A + (size_t)(bm + arow) * K + k0 + acol4);
        As[acol4 + 0][arow] = a4.x;
        As[acol4 + 1][arow] = a4.y;
        As[acol4 + 2][arow] = a4.z;
        As[acol4 + 3][arow] = a4.w;

        int gcol = bn + bcol;
        if (gcol + 3 < N) {
            // rows of B may be only 8B-aligned (N=16386) -> float2 pairs
            const float2* bp = (const float2*)(Bm + (size_t)(k0 + brow) * N + gcol);
            float2 b0 = bp[0], b1 = bp[1];
            Bs[brow][bcol + 0] = b0.x; Bs[brow][bcol + 1] = b0.y;
            Bs[brow][bcol + 2] = b1.x; Bs[brow][bcol + 3] = b1.y;
        } else {
            for (int j = 0; j < 4; ++j)
                Bs[brow][bcol + j] =
                    (gcol + j < N) ? Bm[(size_t)(k0 + brow) * N + gcol + j] : 0.0f;
        }
        __syncthreads();

#pragma unroll
        for (int k = 0; k < BK; ++k) {
            float4 av = *(const float4*)&As[k][tr * 4];
            float4 bv = *(const float4*)&Bs[k][tc * 4];
            float a[4] = {av.x, av.y, av.z, av.w};
            float b[4] = {bv.x, bv.y, bv.z, bv.w};
#pragma unroll
            for (int i = 0; i < 4; ++i)
#pragma unroll
                for (int j = 0; j < 4; ++j)
                    acc[i][j] = fmaf(a[i], b[j], acc[i][j]);
        }
        __syncthreads();
    }

#pragma unroll
    for (int i = 0; i < 4; ++i) {
        int row = bm + tr * 4 + i;
#pragma unroll
        for (int j = 0; j < 4; ++j) {
            int col = bn + tc * 4 + j;
            if (col < N) {
                float v = acc[i][j] + bias[col];
                if (dogelu) v = gelu_new(v);
                if (res) v += res[(size_t)row * N + col];
                C[(size_t)row * N + col] = v;
            }
        }
    }
}

// ---------------------------------------------------------------- attention
// One wave per query row. qkv layout: [B*S, 3*D]; head h occupies cols
// h*64..h*64+63 within each D-sized chunk (q | k | v).
__global__ __launch_bounds__(256) void attn_kernel(
    const float* __restrict__ qkv, float* __restrict__ o)
{
    __shared__ float sc[4][S];   // per-wave score rows
    int lane = threadIdx.x & 63;
    int wv   = threadIdx.x >> 6;
    int bh = blockIdx.y;         // b*H + h
    int b = bh / H, h = bh % H;
    int q = blockIdx.x * 4 + wv;

    const size_t rs = 3 * D;
    const float* qp = qkv + (size_t)(b * S + q) * rs + h * DH;
    const float* kb = qkv + (size_t)(b * S) * rs + D + h * DH;
    const float* vb = kb + D;

    float qv = qp[lane] * 0.125f;        // 1/sqrt(64)
    float m = -1e30f;
    for (int k = 0; k <= q; ++k) {
        float p = qv * kb[(size_t)k * rs + lane];
        for (int off = 32; off; off >>= 1) p += __shfl_xor(p, off);
        if (lane == 0) sc[wv][k] = p;
        m = fmaxf(m, p);
    }
    // softmax (masked entries at -10000 underflow to exactly 0 -> skip k>q)
    float ls = 0.0f;
    for (int k = lane; k <= q; k += 64) {
        float e = __expf(sc[wv][k] - m);
        sc[wv][k] = e;
        ls += e;
    }
    for (int off = 32; off; off >>= 1) ls += __shfl_xor(ls, off);
    float inv = 1.0f / ls;

    float acc = 0.0f;
    for (int k = 0; k <= q; ++k)
        acc = fmaf(sc[wv][k], vb[(size_t)k * rs + lane], acc);

    o[(size_t)(b * S + q) * D + h * DH + lane] = acc * inv;
}

// ---------------------------------------------------------------- launch
extern "C" void kernel_launch(void* const* d_in, const int* in_sizes, int n_in,
                              void* d_out, int out_size, void* d_ws, size_t ws_size,
                              hipStream_t stream)
{
    const int*   ids    = (const int*)d_in[0];
    const int*   tts    = (const int*)d_in[1];
    const float* wte    = (const float*)d_in[2];
    const float* wtte   = (const float*)d_in[3];
    const float* wpe    = (const float*)d_in[4];
    const float* ln1_w  = (const float*)d_in[5];
    const float* ln1_b  = (const float*)d_in[6];
    const float* attn_w = (const float*)d_in[7];
    const float* attn_b = (const float*)d_in[8];
    const float* atp_w  = (const float*)d_in[9];
    const float* atp_b  = (const float*)d_in[10];
    const float* ln2_w  = (const float*)d_in[11];
    const float* ln2_b  = (const float*)d_in[12];
    const float* fc_w   = (const float*)d_in[13];
    const float* fc_b   = (const float*)d_in[14];
    const float* mlp_w  = (const float*)d_in[15];
    const float* mlp_b  = (const float*)d_in[16];
    const float* lnf_w  = (const float*)d_in[17];
    const float* lnf_b  = (const float*)d_in[18];
    const float* head_w = (const float*)d_in[19];
    const float* head_b = (const float*)d_in[20];
    float* out = (float*)d_out;

    // workspace layout (floats)
    float* h   = (float*)d_ws;              // 2048*1024
    float* x   = h   + (size_t)M_ROWS * D;  // 2048*1024
    float* qkv = x   + (size_t)M_ROWS * D;  // 2048*3072
    float* o   = qkv + (size_t)M_ROWS * 3 * D; // 2048*1024
    float* m1  = o   + (size_t)M_ROWS * D;  // 2048*4096

    embed_kernel<<<M_ROWS, 256, 0, stream>>>(ids, tts, wte, wtte, wpe, h);

    for (int l = 0; l < L; ++l) {
        ln_kernel<<<M_ROWS, 256, 0, stream>>>(h, ln1_w + l * D, ln1_b + l * D, x);

        gemm_kernel<<<dim3(3 * D / BN, M_ROWS / BM), 256, 0, stream>>>(
            x, attn_w + (size_t)l * D * 3 * D, attn_b + (size_t)l * 3 * D,
            nullptr, qkv, M_ROWS, 3 * D, D, 0);

        attn_kernel<<<dim3(S / 4, B * H), 256, 0, stream>>>(qkv, o);

        gemm_kernel<<<dim3(D / BN, M_ROWS / BM), 256, 0, stream>>>(
            o, atp_w + (size_t)l * D * D, atp_b + (size_t)l * D,
            h, h, M_ROWS, D, D, 0);

        ln_kernel<<<M_ROWS, 256, 0, stream>>>(h, ln2_w + l * D, ln2_b + l * D, x);

        gemm_kernel<<<dim3(4 * D / BN, M_ROWS / BM), 256, 0, stream>>>(
            x, fc_w + (size_t)l * D * 4 * D, fc_b + (size_t)l * 4 * D,
            nullptr, m1, M_ROWS, 4 * D, D, 1);

        gemm_kernel<<<dim3(D / BN, M_ROWS / BM), 256, 0, stream>>>(
            m1, mlp_w + (size_t)l * 4 * D * D, mlp_b + (size_t)l * D,
            h, h, M_ROWS, D, 4 * D, 0);
    }

    ln_kernel<<<M_ROWS, 256, 0, stream>>>(h, lnf_w, lnf_b, x);

    gemm_kernel<<<dim3((V + BN - 1) / BN, M_ROWS / BM), 256, 0, stream>>>(
        x, head_w, head_b, nullptr, out, M_ROWS, V, D, 0);
}

// Round 2
// 12689.923 us; speedup vs baseline: 1.6864x; 1.6864x over previous
//
#include <hip/hip_runtime.h>
#include <hip/hip_bf16.h>

#define L 12
#define D 1024
#define H 16
#define DH 64
#define S 512
#define B 4
#define V 16386
#define NT 16
#define M_ROWS (B * S)   // 2048

// ---------------------------------------------------------------- embedding
__global__ __launch_bounds__(256) void embed_kernel(
    const int* __restrict__ ids, const int* __restrict__ tts,
    const float* __restrict__ wte, const float* __restrict__ wtte,
    const float* __restrict__ wpe, float* __restrict__ h)
{
    int row = blockIdx.x;            // b*S + s
    int s = row % S;
    int id = ids[row], tt = tts[row];
    int c = threadIdx.x * 4;         // 256 threads * 4 = 1024 = D
    const float4 a = *(const float4*)(wte  + (size_t)id * D + c);
    const float4 p = *(const float4*)(wpe  + (size_t)s  * D + c);
    const float4 t = *(const float4*)(wtte + (size_t)tt * D + c);
    float4 r;
    r.x = a.x + p.x + t.x; r.y = a.y + p.y + t.y;
    r.z = a.z + p.z + t.z; r.w = a.w + p.w + t.w;
    *(float4*)(h + (size_t)row * D + c) = r;
}

// ---------------------------------------------------------------- layernorm
__global__ __launch_bounds__(256) void ln_kernel(
    const float* __restrict__ x, const float* __restrict__ w,
    const float* __restrict__ b, float* __restrict__ y)
{
    int row = blockIdx.x;
    int c = threadIdx.x * 4;
    const float* xr = x + (size_t)row * D;
    float4 v = *(const float4*)(xr + c);
    float s  = v.x + v.y + v.z + v.w;
    float ss = v.x*v.x + v.y*v.y + v.z*v.z + v.w*v.w;
    for (int off = 32; off; off >>= 1) {
        s  += __shfl_xor(s, off);
        ss += __shfl_xor(ss, off);
    }
    __shared__ float sm[8];
    int lane = threadIdx.x & 63, wv = threadIdx.x >> 6;
    if (lane == 0) { sm[wv] = s; sm[4 + wv] = ss; }
    __syncthreads();
    s  = sm[0] + sm[1] + sm[2] + sm[3];
    ss = sm[4] + sm[5] + sm[6] + sm[7];
    float mu  = s * (1.0f / D);
    float var = ss * (1.0f / D) - mu * mu;
    float rstd = rsqrtf(var + 1e-5f);
    float4 wv4 = *(const float4*)(w + c);
    float4 bv4 = *(const float4*)(b + c);
    float4 o;
    o.x = (v.x - mu) * rstd * wv4.x + bv4.x;
    o.y = (v.y - mu) * rstd * wv4.y + bv4.y;
    o.z = (v.z - mu) * rstd * wv4.z + bv4.z;
    o.w = (v.w - mu) * rstd * wv4.w + bv4.w;
    *(float4*)(y + (size_t)row * D + c) = o;
}

// ---------------------------------------------------------------- GEMM
#define BM 64
#define BN 64
#define BK 16

__device__ inline float gelu_new(float x)
{
    float a = 0.7978845608028654f * (x + 0.044715f * x * x * x);
    float e = __expf(-2.0f * fabsf(a));          // tanh via exp, overflow-safe
    float t = (1.0f - e) / (1.0f + e);
    t = (a >= 0.0f) ? t : -t;
    return 0.5f * x * (1.0f + t);
}

__global__ __launch_bounds__(256) void gemm_kernel(
    const float* __restrict__ A, const float* __restrict__ Bm,
    const float* __restrict__ bias, const float* __restrict__ res,
    float* __restrict__ C, int M, int N, int K, int dogelu)
{
    __shared__ float As[BK][BM + 4];
    __shared__ float Bs[BK][BN + 4];
    int tid = threadIdx.x;
    int bm = blockIdx.y * BM;
    int bn = blockIdx.x * BN;
    int tr = tid / 16;          // 0..15 (row group)
    int tc = tid % 16;          // 0..15 (col group)
    int arow  = tid / 4;        // 0..63
    int acol4 = (tid % 4) * 4;  // 0,4,8,12
    int brow  = tid / 16;       // 0..15
    int bcol  = (tid % 16) * 4; // 0..60

    float acc[4][4] = {};

    for (int k0 = 0; k0 < K; k0 += BK) {
        float4 a4 = *(const float4*)(A + (size_t)(bm + arow) * K + k0 + acol4);
        As[acol4 + 0][arow] = a4.x;
        As[acol4 + 1][arow] = a4.y;
        As[acol4 + 2][arow] = a4.z;
        As[acol4 + 3][arow] = a4.w;

        int gcol = bn + bcol;
        if (gcol + 3 < N) {
            const float2* bp = (const float2*)(Bm + (size_t)(k0 + brow) * N + gcol);
            float2 b0 = bp[0], b1 = bp[1];
            Bs[brow][bcol + 0] = b0.x; Bs[brow][bcol + 1] = b0.y;
            Bs[brow][bcol + 2] = b1.x; Bs[brow][bcol + 3] = b1.y;
        } else {
            for (int j = 0; j < 4; ++j)
                Bs[brow][bcol + j] =
                    (gcol + j < N) ? Bm[(size_t)(k0 + brow) * N + gcol + j] : 0.0f;
        }
        __syncthreads();

#pragma unroll
        for (int k = 0; k < BK; ++k) {
            float4 av = *(const float4*)&As[k][tr * 4];
            float4 bv = *(const float4*)&Bs[k][tc * 4];
            float a[4] = {av.x, av.y, av.z, av.w};
            float b[4] = {bv.x, bv.y, bv.z, bv.w};
#pragma unroll
            for (int i = 0; i < 4; ++i)
#pragma unroll
                for (int j = 0; j < 4; ++j)
                    acc[i][j] = fmaf(a[i], b[j], acc[i][j]);
        }
        __syncthreads();
    }

#pragma unroll
    for (int i = 0; i < 4; ++i) {
        int row = bm + tr * 4 + i;
#pragma unroll
        for (int j = 0; j < 4; ++j) {
            int col = bn + tc * 4 + j;
            if (col < N) {
                float v = acc[i][j] + bias[col];
                if (dogelu) v = gelu_new(v);
                if (res) v += res[(size_t)row * N + col];
                C[(size_t)row * N + col] = v;
            }
        }
    }
}

// ---------------------------------------------------------------- attention
// Flash-style: one block = one (b,h) x 64-query tile. Q/K/V 64x64 tiles in
// LDS; 4x4 register microtile for QK^T and PV; online softmax with running
// m/l in registers (row owned by 16 consecutive lanes -> shfl_xor reduce).
#define QT 64
#define KT 64
#define APAD 68   // 64 + 4; row stride 272 B = 16-byte multiple (b128 ok)

__global__ __launch_bounds__(256) void attn_kernel(
    const float* __restrict__ qkv, float* __restrict__ o)
{
    __shared__ float Qs[QT][APAD];
    __shared__ float Ks[KT][APAD];
    __shared__ float Vs[KT][APAD];
    __shared__ float Ps[QT][APAD];

    int tid = threadIdx.x;
    int bh = blockIdx.y;           // b*H + h
    int b = bh >> 4, h = bh & 15;
    int qt = blockIdx.x;           // query tile index

    const size_t rs = 3 * D;
    const float* qb = qkv + (size_t)(b * S) * rs + h * DH;
    const float* kb = qb + D;
    const float* vb = qb + 2 * D;

    int lr = tid >> 4;             // 0..15 (load row within pass)
    int lc = (tid & 15) * 4;       // 0..60

    // load Q tile (pre-scaled by 1/sqrt(DH))
#pragma unroll
    for (int p = 0; p < 4; ++p) {
        int r = p * 16 + lr;
        float4 v = *(const float4*)(qb + (size_t)(qt * QT + r) * rs + lc);
        v.x *= 0.125f; v.y *= 0.125f; v.z *= 0.125f; v.w *= 0.125f;
        *(float4*)&Qs[r][lc] = v;
    }

    int tr = tid >> 4;             // row group: rows tr*4+i
    int tc = tid & 15;             // score cols tc+16j; PV cols tc*4+j

    float acc[4][4] = {};
    float mrun[4] = {-1e30f, -1e30f, -1e30f, -1e30f};
    float lrun[4] = {0.f, 0.f, 0.f, 0.f};

    for (int kt = 0; kt <= qt; ++kt) {
        __syncthreads();   // prev PV done reading Vs/Ps (also orders Qs load)
#pragma unroll
        for (int p = 0; p < 4; ++p) {
            int r = p * 16 + lr;
            *(float4*)&Ks[r][lc] = *(const float4*)(kb + (size_t)(kt * KT + r) * rs + lc);
            *(float4*)&Vs[r][lc] = *(const float4*)(vb + (size_t)(kt * KT + r) * rs + lc);
        }
        __syncthreads();

        // S = Q K^T  (cols strided by 16 -> conflict-free Ks reads)
        float s[4][4] = {};
#pragma unroll
        for (int d = 0; d < DH; d += 4) {
            float4 qv[4], kv[4];
#pragma unroll
            for (int i = 0; i < 4; ++i) qv[i] = *(const float4*)&Qs[tr * 4 + i][d];
#pragma unroll
            for (int j = 0; j < 4; ++j) kv[j] = *(const float4*)&Ks[tc + 16 * j][d];
#pragma unroll
            for (int i = 0; i < 4; ++i)
#pragma unroll
                for (int j = 0; j < 4; ++j)
                    s[i][j] += qv[i].x * kv[j].x + qv[i].y * kv[j].y
                             + qv[i].z * kv[j].z + qv[i].w * kv[j].w;
        }

        // online softmax per row (16 lanes per row -> 4-step shfl reduce)
        bool diag = (kt == qt);
#pragma unroll
        for (int i = 0; i < 4; ++i) {
            int qrow = qt * QT + tr * 4 + i;
            if (diag) {
#pragma unroll
                for (int j = 0; j < 4; ++j) {
                    int kcol = kt * KT + tc + 16 * j;
                    if (kcol > qrow) s[i][j] = -1e30f;
                }
            }
            float rmax = fmaxf(fmaxf(s[i][0], s[i][1]), fmaxf(s[i][2], s[i][3]));
#pragma unroll
            for (int off = 8; off; off >>= 1) rmax = fmaxf(rmax, __shfl_xor(rmax, off));
            float newm = fmaxf(mrun[i], rmax);
            float alpha = __expf(mrun[i] - newm);
            mrun[i] = newm;
            float pj[4], rsum = 0.f;
#pragma unroll
            for (int j = 0; j < 4; ++j) { pj[j] = __expf(s[i][j] - newm); rsum += pj[j]; }
#pragma unroll
            for (int off = 8; off; off >>= 1) rsum += __shfl_xor(rsum, off);
            lrun[i] = lrun[i] * alpha + rsum;
#pragma unroll
            for (int j = 0; j < 4; ++j) {
                acc[i][j] *= alpha;
                Ps[tr * 4 + i][tc + 16 * j] = pj[j];
            }
        }
        __syncthreads();

        // O += P V  (contiguous cols tc*4+j)
#pragma unroll
        for (int k = 0; k < KT; k += 4) {
            float4 pv[4], vv[4];
#pragma unroll
            for (int i = 0; i < 4; ++i) pv[i] = *(const float4*)&Ps[tr * 4 + i][k];
#pragma unroll
            for (int u = 0; u < 4; ++u) vv[u] = *(const float4*)&Vs[k + u][tc * 4];
#pragma unroll
            for (int i = 0; i < 4; ++i) {
                const float* pi = (const float*)&pv[i];
#pragma unroll
                for (int j = 0; j < 4; ++j) {
                    const float* v0 = (const float*)&vv[0];
                    const float* v1 = (const float*)&vv[1];
                    const float* v2 = (const float*)&vv[2];
                    const float* v3 = (const float*)&vv[3];
                    acc[i][j] += pi[0] * v0[j] + pi[1] * v1[j]
                               + pi[2] * v2[j] + pi[3] * v3[j];
                }
            }
        }
    }

    // normalize + write: row covered by 16 lanes, cols tc*4..tc*4+3
#pragma unroll
    for (int i = 0; i < 4; ++i) {
        float inv = 1.0f / lrun[i];
        int qrow = qt * QT + tr * 4 + i;
        float4 ov;
        ov.x = acc[i][0] * inv; ov.y = acc[i][1] * inv;
        ov.z = acc[i][2] * inv; ov.w = acc[i][3] * inv;
        *(float4*)(o + (size_t)(b * S + qrow) * D + h * DH + tc * 4) = ov;
    }
}

// ---------------------------------------------------------------- launch
extern "C" void kernel_launch(void* const* d_in, const int* in_sizes, int n_in,
                              void* d_out, int out_size, void* d_ws, size_t ws_size,
                              hipStream_t stream)
{
    const int*   ids    = (const int*)d_in[0];
    const int*   tts    = (const int*)d_in[1];
    const float* wte    = (const float*)d_in[2];
    const float* wtte   = (const float*)d_in[3];
    const float* wpe    = (const float*)d_in[4];
    const float* ln1_w  = (const float*)d_in[5];
    const float* ln1_b  = (const float*)d_in[6];
    const float* attn_w = (const float*)d_in[7];
    const float* attn_b = (const float*)d_in[8];
    const float* atp_w  = (const float*)d_in[9];
    const float* atp_b  = (const float*)d_in[10];
    const float* ln2_w  = (const float*)d_in[11];
    const float* ln2_b  = (const float*)d_in[12];
    const float* fc_w   = (const float*)d_in[13];
    const float* fc_b   = (const float*)d_in[14];
    const float* mlp_w  = (const float*)d_in[15];
    const float* mlp_b  = (const float*)d_in[16];
    const float* lnf_w  = (const float*)d_in[17];
    const float* lnf_b  = (const float*)d_in[18];
    const float* head_w = (const float*)d_in[19];
    const float* head_b = (const float*)d_in[20];
    float* out = (float*)d_out;

    // workspace layout (floats)
    float* h   = (float*)d_ws;                 // 2048*1024
    float* x   = h   + (size_t)M_ROWS * D;     // 2048*1024
    float* qkv = x   + (size_t)M_ROWS * D;     // 2048*3072
    float* o   = qkv + (size_t)M_ROWS * 3 * D; // 2048*1024
    float* m1  = o   + (size_t)M_ROWS * D;     // 2048*4096

    embed_kernel<<<M_ROWS, 256, 0, stream>>>(ids, tts, wte, wtte, wpe, h);

    for (int l = 0; l < L; ++l) {
        ln_kernel<<<M_ROWS, 256, 0, stream>>>(h, ln1_w + l * D, ln1_b + l * D, x);

        gemm_kernel<<<dim3(3 * D / BN, M_ROWS / BM), 256, 0, stream>>>(
            x, attn_w + (size_t)l * D * 3 * D, attn_b + (size_t)l * 3 * D,
            nullptr, qkv, M_ROWS, 3 * D, D, 0);

        attn_kernel<<<dim3(S / QT, B * H), 256, 0, stream>>>(qkv, o);

        gemm_kernel<<<dim3(D / BN, M_ROWS / BM), 256, 0, stream>>>(
            o, atp_w + (size_t)l * D * D, atp_b + (size_t)l * D,
            h, h, M_ROWS, D, D, 0);

        ln_kernel<<<M_ROWS, 256, 0, stream>>>(h, ln2_w + l * D, ln2_b + l * D, x);

        gemm_kernel<<<dim3(4 * D / BN, M_ROWS / BM), 256, 0, stream>>>(
            x, fc_w + (size_t)l * D * 4 * D, fc_b + (size_t)l * 4 * D,
            nullptr, m1, M_ROWS, 4 * D, D, 1);

        gemm_kernel<<<dim3(D / BN, M_ROWS / BM), 256, 0, stream>>>(
            m1, mlp_w + (size_t)l * 4 * D * D, mlp_b + (size_t)l * D,
            h, h, M_ROWS, D, 4 * D, 0);
    }

    ln_kernel<<<M_ROWS, 256, 0, stream>>>(h, lnf_w, lnf_b, x);

    gemm_kernel<<<dim3((V + BN - 1) / BN, M_ROWS / BM), 256, 0, stream>>>(
        x, head_w, head_b, nullptr, out, M_ROWS, V, D, 0);
}